// Round 15
// baseline (102.719 us; speedup 1.0000x reference)
//
#include <hip/hip_runtime.h>
#include <hip/hip_bf16.h>
#include <stdint.h>

// B=32768 queries, M=4096 memory rows, D=128.
//   logits = Q @ M^T ; attn = softmax(logits) ; out = attn @ M
// v14: fp16 flash kernel, V direct-from-L2. v13's pipe accounting: LDS-read
// 61us (dominant, 64% busy), MFMA 27, VALU 30, VMEM ~8 -> move V off the
// LDS pipe. V fragments are read straight from the (L2-resident, 2MB) ws
// with per-lane coalesced global_load_dwordx4, issued at interval start so
// QK+softmax (~1000cyc) covers L2 latency (T14). K stays LDS-staged for the
// MFMA chain. LDS pipe demand 61->41us; staging halves; V traffic lands on
// the idle VMEM pipe (~31us). Keeps v13's 2-tiles-per-barrier structure.

typedef float    f32x16 __attribute__((ext_vector_type(16)));
typedef _Float16 f16x8  __attribute__((ext_vector_type(8)));
typedef uint32_t u32;

#define AS1 __attribute__((address_space(1)))
#define AS3 __attribute__((address_space(3)))

#define D_DIM 128
#define B_ROWS 32768
#define KTILE_HW 4096     // halfwords per 32-row K tile (8 KB)
#define HALF_TILES 64     // tiles per block

#if __has_builtin(__builtin_amdgcn_exp2f)
#define EXP2F(x) __builtin_amdgcn_exp2f(x)
#else
#define EXP2F(x) exp2f(x)
#endif

__device__ __forceinline__ uint16_t f32_to_f16_bits(float x) {
    _Float16 h = (_Float16)x;
    uint16_t r; __builtin_memcpy(&r, &h, 2);
    return r;
}

// ---------------------------------------------------------------------------
// Prep: memory -> fragment-linear fp16 K and V regions in d_ws (1 MB each).
//   K frag kk: kws[mt*4096 + kk*512 + lane*8 + e]
//              = memory[mt*32 + (lane&31)][kk*16 + (lane>>5)*8 + e]
//   V frag f=ks*4+dt: vws[mt*4096 + f*512 + lane*8 + e]
//              = memory[mt*32 + ks*16 + (lane>>5)*8 + e][dt*32 + (lane&31)]
// ---------------------------------------------------------------------------
__global__ void prep_frags(const float* __restrict__ mem,
                           uint16_t* __restrict__ kws,
                           uint16_t* __restrict__ vws) {
    int t = blockIdx.x * blockDim.x + threadIdx.x;  // 0..65535
    int lane = t & 63;
    int fi = t >> 6;                                // 0..1023
    int f8 = fi & 7, mt = fi >> 3;
    size_t base = (size_t)mt * KTILE_HW;
    {   // K fragment
        int m  = mt * 32 + (lane & 31);
        int d0 = f8 * 16 + (lane >> 5) * 8;
        const float* src = mem + (size_t)m * D_DIM + d0;
        #pragma unroll
        for (int e = 0; e < 8; ++e)
            kws[base + f8 * 512 + lane * 8 + e] = f32_to_f16_bits(src[e]);
    }
    {   // V^T fragment
        int dt = fi & 3, ks = (fi >> 2) & 1;
        int d  = dt * 32 + (lane & 31);
        int m0 = mt * 32 + ks * 16 + (lane >> 5) * 8;
        #pragma unroll
        for (int e = 0; e < 8; ++e)
            vws[base + f8 * 512 + lane * 8 + e] =
                f32_to_f16_bits(mem[(size_t)(m0 + e) * D_DIM + d]);
    }
}

// ---------------------------------------------------------------------------
// Main kernel: 512 blocks x 256 threads (4 waves). Block bx: q-chunk bx>>1,
// memory half bx&1 (64 tiles). K: LDS 4 x 8KB buffers, 2 tiles per barrier.
// V: direct global (L2) loads into registers.
// ---------------------------------------------------------------------------

#define STAGE_K(t_, wb_) do {                                                 \
    const char* g_ = (const char*)(kws + (size_t)(tilebase + (t_)) * KTILE_HW);\
    char* l_ = (char*)&sbuf[wb_][0];                                          \
    _Pragma("unroll")                                                         \
    for (int j_ = 0; j_ < 2; ++j_) {                                          \
        int ch_ = wave * 2 + j_;                                              \
        __builtin_amdgcn_global_load_lds(                                     \
            (const AS1 char*)(g_ + ch_ * 1024 + lane * 16),                   \
            (AS3 char*)(l_ + ch_ * 1024), 16, 0, 0);                          \
    }                                                                         \
} while (0)

#define MFMA_F16(a_, b_, c_) __builtin_amdgcn_mfma_f32_32x32x16_f16(a_, b_, c_, 0, 0, 0)

// Batched V fragment load (global, L2-served, per-lane coalesced).
#define VLOAD(t_, vf_) do {                                                   \
    const uint16_t* vg_ = vws + (size_t)(tilebase + (t_)) * KTILE_HW + lane * 8;\
    _Pragma("unroll")                                                         \
    for (int f_ = 0; f_ < 8; ++f_)                                            \
        vf_[f_] = *(const f16x8*)(vg_ + f_ * 512);                            \
} while (0)

// QK^T for one tile: batch 8 K reads from LDS, two 4-deep chains -> s_.
#define QK(bp_, s_) do {                                                      \
    f16x8 kh_[8];                                                             \
    _Pragma("unroll")                                                         \
    for (int kk_ = 0; kk_ < 8; ++kk_)                                         \
        kh_[kk_] = *(const f16x8*)((bp_) + kk_ * 512);                        \
    f32x16 sA_, sB_;                                                          \
    _Pragma("unroll")                                                         \
    for (int i_ = 0; i_ < 16; ++i_) { sA_[i_] = 0.f; sB_[i_] = 0.f; }         \
    sA_ = MFMA_F16(kh_[0], qh[0], sA_);                                       \
    sB_ = MFMA_F16(kh_[1], qh[1], sB_);                                       \
    sA_ = MFMA_F16(kh_[2], qh[2], sA_);                                       \
    sB_ = MFMA_F16(kh_[3], qh[3], sB_);                                       \
    sA_ = MFMA_F16(kh_[4], qh[4], sA_);                                       \
    sB_ = MFMA_F16(kh_[5], qh[5], sB_);                                       \
    sA_ = MFMA_F16(kh_[6], qh[6], sA_);                                       \
    sB_ = MFMA_F16(kh_[7], qh[7], sB_);                                       \
    s_ = sA_ + sB_;                                                           \
} while (0)

// Online softmax on s_ (Sᵀ layout) then PV with register-resident V frags.
#define SMX_PV(s_, vf_) do {                                                  \
    float a0=fmaxf(s_[0],s_[1]),  a1=fmaxf(s_[2],s_[3]);                      \
    float a2=fmaxf(s_[4],s_[5]),  a3=fmaxf(s_[6],s_[7]);                      \
    float a4=fmaxf(s_[8],s_[9]),  a5=fmaxf(s_[10],s_[11]);                    \
    float a6=fmaxf(s_[12],s_[13]),a7=fmaxf(s_[14],s_[15]);                    \
    float tmax = fmaxf(fmaxf(fmaxf(a0,a1),fmaxf(a2,a3)),                      \
                       fmaxf(fmaxf(a4,a5),fmaxf(a6,a7)));                     \
    tmax = fmaxf(tmax, __shfl_xor(tmax, 32));                                 \
    if (__any(tmax > m_run + 8.0f)) {     /* defer-max (T13) */               \
        float mn = fmaxf(m_run, tmax);                                        \
        float fr = EXP2F(m_run - mn);                                         \
        m_run = mn; l_run *= fr;                                              \
        _Pragma("unroll")                                                     \
        for (int r_ = 0; r_ < 16; ++r_) {                                     \
            O0[r_] *= fr; O1[r_] *= fr; O2[r_] *= fr; O3[r_] *= fr;           \
        }                                                                     \
    }                                                                         \
    _Pragma("unroll")                                                         \
    for (int r_ = 0; r_ < 16; ++r_) s_[r_] = EXP2F(s_[r_] - m_run);           \
    { float q0s=s_[0]+s_[1],  q1s=s_[2]+s_[3],  q2s=s_[4]+s_[5],  q3s=s_[6]+s_[7];   \
      float q4s=s_[8]+s_[9],  q5s=s_[10]+s_[11],q6s=s_[12]+s_[13],q7s=s_[14]+s_[15]; \
      l_run += ((q0s+q1s)+(q2s+q3s)) + ((q4s+q5s)+(q6s+q7s)); }               \
    u32 c_[8];                                                                \
    _Pragma("unroll")                                                         \
    for (int j_ = 0; j_ < 8; ++j_)                                            \
        asm("v_cvt_pkrtz_f16_f32 %0, %1, %2"                                  \
            : "=v"(c_[j_]) : "v"(s_[2*j_]), "v"(s_[2*j_+1]));                 \
    asm("v_permlane32_swap_b32 %0, %1" : "+v"(c_[0]), "+v"(c_[2]));           \
    asm("v_permlane32_swap_b32 %0, %1" : "+v"(c_[1]), "+v"(c_[3]));           \
    asm("v_permlane32_swap_b32 %0, %1" : "+v"(c_[4]), "+v"(c_[6]));           \
    asm("v_permlane32_swap_b32 %0, %1" : "+v"(c_[5]), "+v"(c_[7]));           \
    f16x8 pf0_, pf1_;                                                         \
    { u32 w_[4] = {c_[0], c_[1], c_[2], c_[3]}; __builtin_memcpy(&pf0_, w_, 16); } \
    { u32 w_[4] = {c_[4], c_[5], c_[6], c_[7]}; __builtin_memcpy(&pf1_, w_, 16); } \
    O0 = MFMA_F16(vf_[0], pf0_, O0);                                          \
    O1 = MFMA_F16(vf_[1], pf0_, O1);                                          \
    O2 = MFMA_F16(vf_[2], pf0_, O2);                                          \
    O3 = MFMA_F16(vf_[3], pf0_, O3);                                          \
    O0 = MFMA_F16(vf_[4], pf1_, O0);                                          \
    O1 = MFMA_F16(vf_[5], pf1_, O1);                                          \
    O2 = MFMA_F16(vf_[6], pf1_, O2);                                          \
    O3 = MFMA_F16(vf_[7], pf1_, O3);                                          \
} while (0)

#define PSTORE_TILE(Ot_, t_) do {                                             \
    _Pragma("unroll")                                                         \
    for (int g_ = 0; g_ < 4; ++g_) {                                          \
        float4 v_ = { Ot_[4*g_+0], Ot_[4*g_+1], Ot_[4*g_+2], Ot_[4*g_+3] };   \
        int d_ = (t_) * 32 + 8 * g_ + 4 * hi32;                               \
        *(float4*)(prow + d_) = v_;                                           \
    }                                                                         \
} while (0)

__global__ __launch_bounds__(256, 2)
void attn_main(const float* __restrict__ qin,
               const uint16_t* __restrict__ kws,
               const uint16_t* __restrict__ vws,
               float* __restrict__ out0,      // part-0 un-normalized O (= d_out)
               float* __restrict__ pout1,     // [B_ROWS][128] part-1 partial
               float2* __restrict__ pml) {    // [2][B_ROWS] (m, l)
    __shared__ uint16_t sbuf[4][KTILE_HW];   // 4 x 8 KB = 32 KB

    const int lane = threadIdx.x & 63;
    const int wave = threadIdx.x >> 6;
    const int half = blockIdx.x & 1;
    const int tilebase = half * HALF_TILES;
    const int q0   = (blockIdx.x >> 1) * 128 + wave * 32;
    const int qrow = q0 + (lane & 31);
    const int hi32 = lane >> 5;

    // Q prep: scale by log2(e), convert to fp16 (B-frag of Sᵀ MFMA).
    f16x8 qh[8];
    {
        const float LOG2E = 1.44269504088896340736f;
        #pragma unroll
        for (int kk = 0; kk < 8; ++kk) {
            const float* src = qin + (size_t)qrow * D_DIM + kk * 16 + hi32 * 8;
            float4 a = *(const float4*)(src);
            float4 b = *(const float4*)(src + 4);
            float xs[8] = {a.x, a.y, a.z, a.w, b.x, b.y, b.z, b.w};
            #pragma unroll
            for (int e = 0; e < 8; ++e)
                qh[kk][e] = (_Float16)(xs[e] * LOG2E);
        }
    }

    f32x16 O0, O1, O2, O3;
    #pragma unroll
    for (int i = 0; i < 16; ++i) { O0[i]=0.f; O1[i]=0.f; O2[i]=0.f; O3[i]=0.f; }
    float m_run = -1e30f, l_run = 0.f;

    STAGE_K(0, 0);
    STAGE_K(1, 1);
    __syncthreads();

    // 2 tiles per barrier interval. V loads issued at interval start so the
    // QK MFMA chains + softmax cover the L2 latency (T14 async-split).
    #pragma unroll 1
    for (int t = 0; t < HALF_TILES; t += 2) {
        if (t + 2 < HALF_TILES) STAGE_K(t + 2, (t + 2) & 3);
        if (t + 3 < HALF_TILES) STAGE_K(t + 3, (t + 3) & 3);
        const uint16_t* bp0 = &sbuf[t & 3][0] + lane * 8;
        const uint16_t* bp1 = &sbuf[(t + 1) & 3][0] + lane * 8;

        f16x8 vf0[8], vf1[8];
        VLOAD(t, vf0);
        VLOAD(t + 1, vf1);

        f32x16 s0, s1;
        QK(bp0, s0);          // tile t
        QK(bp1, s1);          // tile t+1 — overlaps softmax(t) below
        SMX_PV(s0, vf0);      // softmax(t) + PV(t)
        SMX_PV(s1, vf1);      // softmax(t+1) + PV(t+1)
        __syncthreads();
    }

    // ---- partial store (un-normalized O, plus m,l) ----
    l_run += __shfl_xor(l_run, 32);     // pair-lane partial sums
    float* prow = (half == 0 ? out0 : pout1) + (size_t)qrow * D_DIM;
    PSTORE_TILE(O0, 0); PSTORE_TILE(O1, 1);
    PSTORE_TILE(O2, 2); PSTORE_TILE(O3, 3);
    if (lane < 32) {
        pml[(size_t)half * B_ROWS + qrow] = make_float2(m_run, l_run);
    }
}

// ---------------------------------------------------------------------------
// Merge: out = (P0*w0 + P1*w1) / (l0*w0 + l1*w1), w_i = exp2(m_i - max).
// P0 lives in d_out (in-place read-modify-write per thread's own float4).
// ---------------------------------------------------------------------------
__global__ __launch_bounds__(256)
void merge_halves(const float* __restrict__ pout1,
                  const float2* __restrict__ pml,
                  float* __restrict__ out) {
    int idx  = blockIdx.x * 256 + threadIdx.x;   // 0 .. 2^20-1
    int row  = idx >> 5;
    int c4   = idx & 31;
    float2 a = pml[row];
    float2 b = pml[B_ROWS + row];
    float mn = fmaxf(a.x, b.x);
    float wa = EXP2F(a.x - mn);
    float wb = EXP2F(b.x - mn);
    float rinv = 1.0f / (a.y * wa + b.y * wb);
    float4* O = (float4*)(out + (size_t)row * D_DIM) + c4;
    const float4* P1 = (const float4*)(pout1 + (size_t)row * D_DIM) + c4;
    float4 p0 = *O, p1 = *P1;
    float4 v;
    v.x = (p0.x * wa + p1.x * wb) * rinv;
    v.y = (p0.y * wa + p1.y * wb) * rinv;
    v.z = (p0.z * wa + p1.z * wb) * rinv;
    v.w = (p0.w * wa + p1.w * wb) * rinv;
    *O = v;
}

extern "C" void kernel_launch(void* const* d_in, const int* in_sizes, int n_in,
                              void* d_out, int out_size, void* d_ws, size_t ws_size,
                              hipStream_t stream) {
    const float* local_stats = (const float*)d_in[0];   // [32768,128] f32
    const float* memory      = (const float*)d_in[1];   // [4096,128]  f32
    float* out = (float*)d_out;                         // [32768,128] f32

    // ws layout: K frags 1MB | V frags 1MB | part-1 partial O 16MB | pml 0.5MB
    uint16_t* kws  = (uint16_t*)d_ws;
    uint16_t* vws  = kws + 128 * KTILE_HW;
    float*   pout1 = (float*)((char*)d_ws + 2 * 1024 * 1024);
    float2*  pml   = (float2*)((char*)pout1 + (size_t)B_ROWS * D_DIM * 4);

    prep_frags<<<256, 256, 0, stream>>>(memory, kws, vws);
    attn_main<<<512, 256, 0, stream>>>(local_stats, kws, vws, out, pout1, pml);
    merge_halves<<<4096, 256, 0, stream>>>(pout1, pml, out);
}